// Round 4
// baseline (453.191 us; speedup 1.0000x reference)
//
#include <hip/hip_runtime.h>

// LIF recurrence: X [B,T,N] f32 -> spikes [B,T,N] f32
// B=32, T=64, N=32768. Independent per (b,n); sequential over t.
// R1: float4/thread, no pipeline -> 169 us (latency-bound, 2.4 TB/s).
// R2: float2/thread + depth-2 prefetch -> ~164 us (slack 240 cyc << 900 cyc
//     HBM latency; depth-2 insufficient).
// R3: depth-8 rolling register prefetch + full unroll + NT stores.
//     (R3 failed compile: __builtin_nontemporal_store needs a NATIVE vector
//     type, not HIP_vector_type -> use ext_vector_type(2) for the store.)
//     Slack = 8 iters x ~120 cyc ~ 960 cyc >= HBM latency; 8 loads x 512 B x
//     32 waves = 128 KB in flight/CU >> ~9 KB needed for peak BW.

constexpr int B = 32;
constexpr int T = 64;
constexpr int N = 32768;
constexpr int N2 = N / 2;          // float2 granularity = 16384
constexpr int NTHREADS = B * N2;   // 524288 threads = 8192 waves
constexpr int D = 8;               // prefetch depth

typedef float vfloat2 __attribute__((ext_vector_type(2)));

__global__ __launch_bounds__(256, 8) void lif_kernel(const float2* __restrict__ X,
                                                     float2* __restrict__ out) {
    // Match numpy's separately-rounded mul/add (no FMA contraction): fusing
    // changes rounding and can flip threshold decisions.
#pragma clang fp contract(off)
    const int i = blockIdx.x * blockDim.x + threadIdx.x;  // [0, B*N2)
    const int b = i >> 14;            // i / N2  (N2 = 16384)
    const int n2 = i & (N2 - 1);      // i % N2
    const int base = b * (T * N2) + n2;   // max ~33.5M, fits int

    float mem0 = 0.f, mem1 = 0.f;
    float ca0 = 0.f, ca1 = 0.f;

    // Prime the 8-deep rolling buffer (8 loads in flight).
    float2 buf[D];
#pragma unroll
    for (int k = 0; k < D; ++k) buf[k] = X[base + k * N2];

#pragma unroll
    for (int t = 0; t < T; ++t) {
        const float2 xv = buf[t % D];      // loaded 8 iterations ago
        // Refill the slot immediately (keeps 8 loads outstanding).
        if (t + D < T) buf[t % D] = X[base + (t + D) * N2];

        vfloat2 sv;
        // elem 0
        {
            float m = mem0 / 5.0f + (1.0f + 0.1f * ca0) * xv.x;
            float s = ((m - 0.5f) > 0.0f) ? 1.0f : 0.0f;
            mem0 = (1.0f - s) * m;
            ca0 = 0.5f * ca0 + (1.0f - s);
            sv.x = s;
        }
        // elem 1
        {
            float m = mem1 / 5.0f + (1.0f + 0.1f * ca1) * xv.y;
            float s = ((m - 0.5f) > 0.0f) ? 1.0f : 0.0f;
            mem1 = (1.0f - s) * m;
            ca1 = 0.5f * ca1 + (1.0f - s);
            sv.y = s;
        }

        // Output is write-once, never re-read: bypass cache pollution.
        __builtin_nontemporal_store(sv, (vfloat2*)&out[base + t * N2]);
    }
}

extern "C" void kernel_launch(void* const* d_in, const int* in_sizes, int n_in,
                              void* d_out, int out_size, void* d_ws, size_t ws_size,
                              hipStream_t stream) {
    const float2* X = (const float2*)d_in[0];
    float2* out = (float2*)d_out;
    const int block = 256;
    const int grid = NTHREADS / block;  // 2048 blocks
    lif_kernel<<<grid, block, 0, stream>>>(X, out);
}

// Round 5
// 450.197 us; speedup vs baseline: 1.0066x; 1.0066x over previous
//
#include <hip/hip_runtime.h>

// LIF recurrence: X [B,T,N] f32 -> spikes [B,T,N] f32
// B=32, T=64, N=32768. Independent per (b,n); sequential over t.
// R1: float4/thread, no pipeline -> 169 us (latency-bound, 2.4 TB/s).
// R2: float2/thread + depth-2 prefetch -> ~164 us (slack too small).
// R4: depth-8 rolling buffer BUT __launch_bounds__(256,8) capped VGPRs at 64
//     -> scheduler sank loads next to uses (VGPR_Count=24 proves the buffer
//     was deleted) -> effective depth 1 -> neutral, 165 us.
// R5: __launch_bounds__(256,4) -> 128-VGPR budget; ~45-reg kernel fits with
//     slack so the 8-deep pipeline survives. In-flight = 16 waves x 8 x 512 B
//     = 64 KB/CU -> BW-bound at the ~10.6 B/cyc/CU HBM ceiling.

constexpr int B = 32;
constexpr int T = 64;
constexpr int N = 32768;
constexpr int N2 = N / 2;          // float2 granularity = 16384
constexpr int NTHREADS = B * N2;   // 524288 threads = 8192 waves
constexpr int D = 8;               // prefetch depth

typedef float vfloat2 __attribute__((ext_vector_type(2)));

__global__ __launch_bounds__(256, 4) void lif_kernel(const float2* __restrict__ X,
                                                     float2* __restrict__ out) {
    // Match numpy's separately-rounded mul/add (no FMA contraction): fusing
    // changes rounding and can flip threshold decisions.
#pragma clang fp contract(off)
    const int i = blockIdx.x * blockDim.x + threadIdx.x;  // [0, B*N2)
    const int b = i >> 14;            // i / N2  (N2 = 16384)
    const int n2 = i & (N2 - 1);      // i % N2
    const int base = b * (T * N2) + n2;   // max ~33.5M, fits int

    float mem0 = 0.f, mem1 = 0.f;
    float ca0 = 0.f, ca1 = 0.f;

    // Prime the 8-deep rolling buffer (8 loads in flight).
    float2 buf[D];
#pragma unroll
    for (int k = 0; k < D; ++k) buf[k] = X[base + k * N2];

#pragma unroll
    for (int t = 0; t < T; ++t) {
        const float2 xv = buf[t % D];      // loaded 8 iterations ago
        // Refill the slot immediately (keeps 8 loads outstanding).
        if (t + D < T) buf[t % D] = X[base + (t + D) * N2];

        vfloat2 sv;
        // elem 0
        {
            float m = mem0 / 5.0f + (1.0f + 0.1f * ca0) * xv.x;
            float s = ((m - 0.5f) > 0.0f) ? 1.0f : 0.0f;
            mem0 = (1.0f - s) * m;
            ca0 = 0.5f * ca0 + (1.0f - s);
            sv.x = s;
        }
        // elem 1
        {
            float m = mem1 / 5.0f + (1.0f + 0.1f * ca1) * xv.y;
            float s = ((m - 0.5f) > 0.0f) ? 1.0f : 0.0f;
            mem1 = (1.0f - s) * m;
            ca1 = 0.5f * ca1 + (1.0f - s);
            sv.y = s;
        }

        // Output is write-once, never re-read: bypass cache pollution.
        __builtin_nontemporal_store(sv, (vfloat2*)&out[base + t * N2]);
    }
}

extern "C" void kernel_launch(void* const* d_in, const int* in_sizes, int n_in,
                              void* d_out, int out_size, void* d_ws, size_t ws_size,
                              hipStream_t stream) {
    const float2* X = (const float2*)d_in[0];
    float2* out = (float2*)d_out;
    const int block = 256;
    const int grid = NTHREADS / block;  // 2048 blocks
    lif_kernel<<<grid, block, 0, stream>>>(X, out);
}